// Round 5
// baseline (330.076 us; speedup 1.0000x reference)
//
#include <hip/hip_runtime.h>
#include <cstdint>
#include <cstddef>

// LIF recurrent SNN, sinabs ThresholdSubtract.
//   B=32 independent batch rows -> 1 block per batch, state in registers.
//   Spikes ~4.4 sigma -> speculate "no spike in chunk", exact replay on hit.
// Round-12: per-wave chunk ownership in the producer = 4-window latency
//   tolerance. LEDGER: R1..R8 consumer-side prefetch defeated by compiler
//   passes. R10 prod/cons depth-2 + shared CU = 4600cy/chunk. R11 (depth-4
//   ring, A/B reg buffers, vmcnt(8), exclusive CUs) = 3190cy/chunk: the
//   producer self-throttles at W = L/2 because issue(c+4) is program-order
//   gated on retire(c+2); measured W implies effective L ~ 6400cy (in-order
//   vmcnt retirement + TA/L2 queueing of 256 lines/window/CU), so latency
//   slack -- not bandwidth -- is the binding constraint.
//   R12: producer wave p owns chunks == p (mod 4) ENTIRELY (32 loads/lane,
//   128 VGPRs buffer; VGPRs are free at 1 block/CU). At window c only wave
//   (c+2)&3 acts: vmcnt(0) [exact: per-wave counter, only its own chunk
//   outstanding, issued 4 windows earlier] -> 32 ds_write_b128 -> issue
//   chunk c+6 -> barrier. Tolerance 2W -> 4W. Consumer/ring/replay parity
//   identical to R11 (slot (c+2)&3 never collides with consumer's c&3).
#define B_       32
#define T_       1000
#define N_       1024
#define THREADS_ 512           // 8 waves: 4 consumer (tid<256) + 4 producer
#define CWAVES_  4
#define CHUNK_   8
#define NCHUNK_  125           // 125*8 = 1000 steps
#define DEPTH_   4             // LDS ring slots
#define SLOT_BYTES_ 32768      // CHUNK_*N_*4
#define ZBLOCKS_ 224           // total grid = 256 blocks = #CUs (1 block/CU)

typedef float v4f __attribute__((ext_vector_type(4)));

__device__ __forceinline__ v4f vmax4(v4f a, v4f b) {
  v4f r;
  r.x = fmaxf(a.x, b.x); r.y = fmaxf(a.y, b.y);
  r.z = fmaxf(a.z, b.z); r.w = fmaxf(a.w, b.w);
  return r;
}

// Inline-asm LDS read: opaque to SIInsertWaitcnts; ordered manually with
// lgkmcnt(0) + sched_barrier(0) (rule #18).
#define DSRD(dst, base, imm)                                                 \
  asm volatile("ds_read_b128 %0, %1 offset:" #imm : "=v"(dst) : "v"(base))

// One producer row: 4 col-group loads off one base pointer (imm offsets
// 0/1024/2048/3072 B). Early-clobber: outputs must not alias the addr pair.
#define GROW(d0,d1,d2,d3, p)                                                 \
  asm volatile("global_load_dwordx4 %0, %4, off\n\t"                         \
               "global_load_dwordx4 %1, %4, off offset:1024\n\t"             \
               "global_load_dwordx4 %2, %4, off offset:2048\n\t"             \
               "global_load_dwordx4 %3, %4, off offset:3072"                 \
               : "=&v"(d0), "=&v"(d1), "=&v"(d2), "=&v"(d3) : "v"(p))

// Issue ALL of chunk cc (8 rows x 4 col-groups) into the 32 named P regs.
#define GIS32(cc)                                                            \
  do {                                                                       \
    const float* _pr = sbase + (size_t)(cc) * (CHUNK_ * N_);                 \
    GROW(P00,P01,P02,P03, _pr + 0 * N_);                                     \
    GROW(P10,P11,P12,P13, _pr + 1 * N_);                                     \
    GROW(P20,P21,P22,P23, _pr + 2 * N_);                                     \
    GROW(P30,P31,P32,P33, _pr + 3 * N_);                                     \
    GROW(P40,P41,P42,P43, _pr + 4 * N_);                                     \
    GROW(P50,P51,P52,P53, _pr + 5 * N_);                                     \
    GROW(P60,P61,P62,P63, _pr + 6 * N_);                                     \
    GROW(P70,P71,P72,P73, _pr + 7 * N_);                                     \
    __builtin_amdgcn_sched_barrier(0);  /* pin issue point */                \
  } while (0)

// Publish a landed chunk to its ring slot (32 ds_write_b128, imm offsets).
#define WRS32(cc)                                                            \
  do {                                                                       \
    const int _sl = (cc) & (DEPTH_ - 1);                                     \
    xring[_sl][0][lane] = P00; xring[_sl][0][lane+64] = P01;                 \
    xring[_sl][0][lane+128] = P02; xring[_sl][0][lane+192] = P03;            \
    xring[_sl][1][lane] = P10; xring[_sl][1][lane+64] = P11;                 \
    xring[_sl][1][lane+128] = P12; xring[_sl][1][lane+192] = P13;            \
    xring[_sl][2][lane] = P20; xring[_sl][2][lane+64] = P21;                 \
    xring[_sl][2][lane+128] = P22; xring[_sl][2][lane+192] = P23;            \
    xring[_sl][3][lane] = P30; xring[_sl][3][lane+64] = P31;                 \
    xring[_sl][3][lane+128] = P32; xring[_sl][3][lane+192] = P33;            \
    xring[_sl][4][lane] = P40; xring[_sl][4][lane+64] = P41;                 \
    xring[_sl][4][lane+128] = P42; xring[_sl][4][lane+192] = P43;            \
    xring[_sl][5][lane] = P50; xring[_sl][5][lane+64] = P51;                 \
    xring[_sl][5][lane+128] = P52; xring[_sl][5][lane+192] = P53;            \
    xring[_sl][6][lane] = P60; xring[_sl][6][lane+64] = P61;                 \
    xring[_sl][6][lane+128] = P62; xring[_sl][6][lane+192] = P63;            \
    xring[_sl][7][lane] = P70; xring[_sl][7][lane+64] = P71;                 \
    xring[_sl][7][lane+128] = P72; xring[_sl][7][lane+192] = P73;            \
  } while (0)

// Wait this wave's own outstanding loads (exact: per-wave vmcnt counter).
#define VM0W                                                                 \
  do {                                                                       \
    asm volatile("s_waitcnt vmcnt(0)" ::: "memory");                         \
    __builtin_amdgcn_sched_barrier(0);  /* no store hoist above the wait */  \
  } while (0)

#define SPEC_STEP(xf)                                                        \
  do {                                                                       \
    cmax = vmax4(cmax, st);                                                  \
    v4f _t = (xf) + rr;                                                      \
    st = st * 0.9f + 0.1f * _t;                                              \
    rr = brec;                                                               \
  } while (0)

// Consumer: process chunk cc from ring slot cc&3 (published two windows
// earlier). Speculative no-spike pass; ballot exchange; exact replay (rare).
// Exactly ONE __syncthreads per chunk (+8 in replay).
#define PROCESS(cc)                                                          \
  do {                                                                       \
    unsigned _a = xb + (unsigned)(((cc) & (DEPTH_ - 1)) * SLOT_BYTES_)       \
                     + ((unsigned)tid << 4);                                 \
    v4f _x0, _x1, _x2, _x3, _x4, _x5, _x6, _x7;                              \
    DSRD(_x0, _a, 0);     DSRD(_x1, _a, 4096);                               \
    DSRD(_x2, _a, 8192);  DSRD(_x3, _a, 12288);                              \
    DSRD(_x4, _a, 16384); DSRD(_x5, _a, 20480);                              \
    DSRD(_x6, _a, 24576); DSRD(_x7, _a, 28672);                              \
    asm volatile("s_waitcnt lgkmcnt(0)");                                    \
    __builtin_amdgcn_sched_barrier(0);  /* rule #18: no VALU hoist above */  \
    v4f st = state, rr = rec, cmax = state;                                  \
    SPEC_STEP(_x0); SPEC_STEP(_x1); SPEC_STEP(_x2); SPEC_STEP(_x3);          \
    SPEC_STEP(_x4); SPEC_STEP(_x5); SPEC_STEP(_x6); SPEC_STEP(_x7);          \
    float _m = fmaxf(fmaxf(cmax.x, cmax.y), fmaxf(cmax.z, cmax.w));          \
    int _any = (_m >= 1.0f);                                                 \
    const int _p = (cc) & 1;                                                 \
    unsigned long long _wm = __ballot(_any);                                 \
    if (lane == 0) s_cmask[_p][wv] = _wm;                                    \
    __syncthreads();                                                         \
    unsigned long long _ab =                                                 \
        s_cmask[_p][0] | s_cmask[_p][1] | s_cmask[_p][2] | s_cmask[_p][3];   \
    if (_ab == 0ULL) { state = st; rec = brec; }                             \
    else { replay(cc); }                                                     \
  } while (0)

__global__ __launch_bounds__(THREADS_, 1)
void lif_fused(const float* __restrict__ x, const float* __restrict__ w,
               const float* __restrict__ brec_g, float* __restrict__ out,
               unsigned long long* __restrict__ ws_rec,
               unsigned int* __restrict__ ws_cnt, int cap)
{
  // ---------------- zero path: blocks >= 32 clear the output ----------------
  if (blockIdx.x >= B_) {
    const size_t n4 = (size_t)B_ * T_ * N_ / 4;
    size_t i = (size_t)(blockIdx.x - B_) * THREADS_ + threadIdx.x;
    const size_t stride = (size_t)(gridDim.x - B_) * THREADS_;
    v4f* o4 = (v4f*)out;
    v4f z = (v4f)(0.f);
    for (; i < n4; i += stride) __builtin_nontemporal_store(z, &o4[i]);
    return;
  }

  // ---------------- lif path: blocks 0..31, one batch row each --------------
  const int b    = blockIdx.x;
  const int tid  = threadIdx.x;
  const int lane = tid & 63;
  const int wv   = tid >> 6;

  // x staging ring: 4 slots x 32KB, layout [slot][row k][v4 column 0..255].
  // 139KB total LDS -> hardware-enforced 1 block/CU (exclusivity).
  __shared__ v4f xring[DEPTH_][CHUNK_][N_ / 4];
  // Parity-double-buffered exchange: one barrier per chunk/step, no resets.
  __shared__ unsigned long long s_cmask[2][CWAVES_];
  __shared__ unsigned long long s_mask [2][CWAVES_];
  __shared__ v4f                s_val  [2][CWAVES_ * 64];
  __shared__ unsigned int       s_spkcnt;

  if (tid == 0) s_spkcnt = 0;   // visible to all after the prologue barrier

  const float* xg_base = x + (size_t)b * T_ * N_;

  if (wv >= CWAVES_) {
    // ------------------------- producer role ------------------------------
    // Wave pw owns chunks == pw (mod 4): ALL 256 v4-columns of each of its
    // chunks (lane l loads cols l, l+64, l+128, l+192 of 8 rows = 32 x16B).
    // Window c: only wave (c+2)&3 acts -> vmcnt(0) is exact (its only
    // outstanding loads are chunk c+2, issued at window c-4).
    const int pw = wv - CWAVES_;             // 0..3
    const float* sbase = xg_base + ((size_t)lane << 2);

    auto replaycheck = [&](int c) {
      const int p = c & 1;
      unsigned long long ab =
          s_cmask[p][0] | s_cmask[p][1] | s_cmask[p][2] | s_cmask[p][3];
      if (ab != 0ULL) {
#pragma unroll 1
        for (int k = 0; k < CHUNK_; ++k) __syncthreads();  // mirror replay
      }
    };

    v4f P00,P01,P02,P03, P10,P11,P12,P13, P20,P21,P22,P23, P30,P31,P32,P33,
        P40,P41,P42,P43, P50,P51,P52,P53, P60,P61,P62,P63, P70,P71,P72,P73;

    // prologue: all 4 waves issue their first chunk; waves 0,1 publish
    // slots 0,1 and issue chunks 4,5; chunks 2,3 stay in flight for
    // windows 0,1.
    GIS32(pw);
    if (pw < 2) {
      VM0W;
      WRS32(pw);
      GIS32(pw + 4);
    }
    __syncthreads();                      // prologue barrier (slots 0,1 ready)

#pragma unroll 1
    for (int c = 0; c < NCHUNK_; ++c) {
      const int wr = c + 2;               // chunk to publish this window
      if ((wr & 3) == pw && wr < NCHUNK_) {
        VM0W;                             // chunk wr landed (issued c-4)
        WRS32(wr);
        if (wr + 4 < NCHUNK_) GIS32(wr + 4);
      }
      __syncthreads();                    // barrier c
      replaycheck(c);
    }
    __syncthreads();                      // epilogue barrier
    return;
  }

  // ------------------------- consumer role --------------------------------
  __builtin_amdgcn_s_setprio(1);          // T5: favor the latency-critical role
  const int n0 = tid << 2;                // this thread's 4 neurons

  // LDS byte offset of the ring base for the pinned asm ds_reads
  const unsigned xb =
      (unsigned)(uintptr_t)(__attribute__((address_space(3))) void*)xring;

  v4f state = (v4f)(0.f);
  v4f rec   = (v4f)(0.f);                 // initial carry rec = 0 (NOT b_rec)
  const v4f brec = *(const v4f*)(brec_g + n0);

  // Exact replay of chunk cc (rare): x comes from ring slot cc&3 (valid until
  // chunk cc+4 is published in window cc+2; producers are parked in the
  // matching dummy barriers during replay). Per-step spike exchange, sparse
  // rank-1 rec update, spike records.
  auto replay = [&](int cc) {
    v4f st = state;
    v4f r  = rec;
    const int sl = cc & (DEPTH_ - 1);
#pragma unroll 1
    for (int k = 0; k < CHUNK_; ++k) {
      const int q = k & 1;
      v4f xv = xring[sl][k][tid];
      float tx = xv.x + r.x, ty = xv.y + r.y, tz = xv.z + r.z, tw = xv.w + r.w;
      float ax = (st.x > 0.f) ? floorf(st.x) : 0.f;
      float ay = (st.y > 0.f) ? floorf(st.y) : 0.f;
      float az = (st.z > 0.f) ? floorf(st.z) : 0.f;
      float aw = (st.w > 0.f) ? floorf(st.w) : 0.f;
      int ms = (ax != 0.f) | (ay != 0.f) | (az != 0.f) | (aw != 0.f);
      if (ms) {
        v4f v; v.x = ax; v.y = ay; v.z = az; v.w = aw;
        s_val[q][tid] = v;
        unsigned int off = (unsigned int)((cc * CHUNK_ + k) * N_ + n0);
        float av[4] = {ax, ay, az, aw};
#pragma unroll
        for (int e = 0; e < 4; ++e) {
          if (av[e] != 0.f) {
            unsigned int idx = atomicAdd(&s_spkcnt, 1u);
            if ((int)idx < cap)
              ws_rec[(size_t)b * cap + idx] =
                  ((unsigned long long)(off + e) << 32) |
                  (unsigned long long)__float_as_uint(av[e]);
          }
        }
      }
      unsigned long long sm = __ballot(ms);
      if (lane == 0) s_mask[q][wv] = sm;
      st.x = (st.x - ax) * 0.9f + 0.1f * tx;
      st.y = (st.y - ay) * 0.9f + 0.1f * ty;
      st.z = (st.z - az) * 0.9f + 0.1f * tz;
      st.w = (st.w - aw) * 0.9f + 0.1f * tw;
      __syncthreads();                    // replay barrier (producers mirror)
      // sparse rank-1 rec update: rec[n] = b_rec[n] + sum_j act[j]*w[n][j]
      v4f racc = brec;
#pragma unroll 1
      for (int w2 = 0; w2 < CWAVES_; ++w2) {
        unsigned long long mm = s_mask[q][w2];
        while (mm) {
          int l = __builtin_ctzll(mm);
          mm &= mm - 1;
          int j = (w2 << 6) + l;
          v4f v = s_val[q][j];
          int jn = j << 2;
          if (v.x != 0.f) {
            racc.x += v.x * w[(size_t)(n0 + 0) * N_ + jn];
            racc.y += v.x * w[(size_t)(n0 + 1) * N_ + jn];
            racc.z += v.x * w[(size_t)(n0 + 2) * N_ + jn];
            racc.w += v.x * w[(size_t)(n0 + 3) * N_ + jn];
          }
          if (v.y != 0.f) {
            int j1 = jn + 1;
            racc.x += v.y * w[(size_t)(n0 + 0) * N_ + j1];
            racc.y += v.y * w[(size_t)(n0 + 1) * N_ + j1];
            racc.z += v.y * w[(size_t)(n0 + 2) * N_ + j1];
            racc.w += v.y * w[(size_t)(n0 + 3) * N_ + j1];
          }
          if (v.z != 0.f) {
            int j2 = jn + 2;
            racc.x += v.z * w[(size_t)(n0 + 0) * N_ + j2];
            racc.y += v.z * w[(size_t)(n0 + 1) * N_ + j2];
            racc.z += v.z * w[(size_t)(n0 + 2) * N_ + j2];
            racc.w += v.z * w[(size_t)(n0 + 3) * N_ + j2];
          }
          if (v.w != 0.f) {
            int j3 = jn + 3;
            racc.x += v.w * w[(size_t)(n0 + 0) * N_ + j3];
            racc.y += v.w * w[(size_t)(n0 + 1) * N_ + j3];
            racc.z += v.w * w[(size_t)(n0 + 2) * N_ + j3];
            racc.w += v.w * w[(size_t)(n0 + 3) * N_ + j3];
          }
        }
      }
      r = racc;
    }
    state = st;
    rec   = r;
  };

  __syncthreads();                        // prologue barrier (slots 0,1 ready)
#pragma unroll 1
  for (int c = 0; c < NCHUNK_; ++c) {
    PROCESS(c);
  }

  __syncthreads();                        // epilogue (all replay appends done)
  if (tid == 0) ws_cnt[b] = s_spkcnt;     // written unconditionally (ws poisoned)
}

// Apply the (few hundred) recorded spikes onto the zeroed output.
__global__ void scatter_spikes(const unsigned long long* __restrict__ rec,
                               const unsigned int* __restrict__ cnt,
                               float* __restrict__ out, int cap)
{
  int b = blockIdx.x;
  unsigned int n = cnt[b];
  if ((int)n > cap) n = cap;
  for (unsigned int i = threadIdx.x; i < n; i += blockDim.x) {
    unsigned long long r = rec[(size_t)b * cap + i];
    unsigned int off = (unsigned int)(r >> 32);
    float v = __uint_as_float((unsigned int)r);
    out[(size_t)b * (T_ * N_) + off] = v;
  }
}

extern "C" void kernel_launch(void* const* d_in, const int* in_sizes, int n_in,
                              void* d_out, int out_size, void* d_ws, size_t ws_size,
                              hipStream_t stream) {
  const float* x  = (const float*)d_in[0]; // [B,T,N] input_current
  const float* w  = (const float*)d_in[1]; // [N,N] w_rec (row-major [out,in])
  const float* br = (const float*)d_in[2]; // [N] b_rec
  float* out = (float*)d_out;              // [B,T,N] spikes

  // spike-record workspace layout: [32][cap] u64 records, then [32] u32 counts
  int cap = 4096;
  size_t need = (size_t)B_ * cap * 8 + B_ * 4;
  if (ws_size < need && ws_size > 256)
    cap = (int)((ws_size - 256) / ((size_t)B_ * 8));
  unsigned long long* rec = (unsigned long long*)d_ws;
  unsigned int* cnt = (unsigned int*)((char*)d_ws + (size_t)B_ * cap * 8);

  // blocks 0..31: sequential LIF scan (1 block/batch row, exclusive CU);
  // blocks 32..255: zero the output on the remaining CUs (1 block/CU).
  lif_fused<<<B_ + ZBLOCKS_, THREADS_, 0, stream>>>(x, w, br, out, rec, cnt, cap);
  scatter_spikes<<<B_, THREADS_, 0, stream>>>(rec, cnt, out, cap);
}